// Round 1
// baseline (303.877 us; speedup 1.0000x reference)
//
#include <hip/hip_runtime.h>
#include <hip/hip_bf16.h>

// Problem constants
#define T_IN   16384
#define T_OUT  16376
#define CIN    64
#define NF     64
#define KT     9
#define NB     32
#define TILE   128                 // output rows per tile
#define ROWS   (TILE + KT - 1)     // 136 staged input rows
#define LDS_STRIDE 72              // shorts per row: 64 + 8 pad (144 B, breaks 128B stride)
#define TILES_PER_BATCH 128        // ceil(16376/128); last tile has 120 valid rows
#define NTILES (NB * TILES_PER_BATCH)   // 4096
#define NBLOCKS 512
#define TILE_ITERS (NTILES / NBLOCKS)   // 8
#define CHUNKS (ROWS * 16)         // 2176 float4 chunks per tile
#define CPT 9                      // ceil(2176/256) chunks per thread

typedef __bf16 bf16x8 __attribute__((ext_vector_type(8)));
typedef unsigned short u16x8 __attribute__((ext_vector_type(8)));
typedef unsigned short u16x4 __attribute__((ext_vector_type(4)));
typedef float f32x16 __attribute__((ext_vector_type(16)));

// fp32 -> bf16 round-to-nearest-even (bit twiddle; avoids relying on __bf16 conversions)
__device__ __forceinline__ unsigned short f2bf(float f) {
    unsigned u = __builtin_bit_cast(unsigned, f);
    u += 0x7FFFu + ((u >> 16) & 1u);
    return (unsigned short)(u >> 16);
}

__global__ __launch_bounds__(256, 2) void conv1d_mfma_kernel(
    const float* __restrict__ x,   // [32][16384][64]
    const float* __restrict__ w,   // [64][9][64]
    const float* __restrict__ b,   // [64]
    float* __restrict__ out)       // [32][16376][64]
{
    // Double-buffered bf16 input tile
    __shared__ __attribute__((aligned(16))) unsigned short ldsX[2][ROWS * LDS_STRIDE];

    const int tid  = threadIdx.x;
    const int lane = tid & 63;
    const int wv   = tid >> 6;        // 4 waves
    const int half = lane >> 5;       // 0/1: k-half of MFMA operand
    const int l31  = lane & 31;
    const int fh   = wv & 1;          // filter half (0: f 0..31, 1: f 32..63)
    const int rh   = wv >> 1;         // row half (0: rows 0..63, 1: rows 64..127)
    const int fbase = fh * 32;
    const int rbase = rh * 64;
    const int fcol  = fbase + l31;    // this lane's output filter column

    // ---- Load all weight B-fragments into registers (once per block) ----
    // B[k_inner][n] layout for mfma_f32_32x32x16_bf16: n = lane&31, k_inner = (lane>>5)*8 + j
    // Global w element: w[f][tap][c], c = s*16 + half*8 + j
    bf16x8 Bf[KT][4];
#pragma unroll
    for (int k = 0; k < KT; ++k) {
#pragma unroll
        for (int s = 0; s < 4; ++s) {
            const float* wp = w + (size_t)fcol * (KT * CIN) + k * CIN + s * 16 + half * 8;
            const float4 w0 = *(const float4*)(wp);
            const float4 w1 = *(const float4*)(wp + 4);
            u16x8 t;
            t[0] = f2bf(w0.x); t[1] = f2bf(w0.y); t[2] = f2bf(w0.z); t[3] = f2bf(w0.w);
            t[4] = f2bf(w1.x); t[5] = f2bf(w1.y); t[6] = f2bf(w1.z); t[7] = f2bf(w1.w);
            Bf[k][s] = __builtin_bit_cast(bf16x8, t);
        }
    }
    const float bias = b[fcol];

    // Per-thread staged chunks for the NEXT tile (in-flight while current tile computes)
    float4 st[CPT];

    // ---- Prologue: stage tile 0 of this block into buffer 0 ----
    {
        const int g  = blockIdx.x * TILE_ITERS;
        const int bb = g >> 7;
        const int t0 = (g & 127) << 7;
#pragma unroll
        for (int i = 0; i < CPT; ++i) {
            const int idx = i * 256 + tid;
            if (idx < CHUNKS) {
                const int r  = idx >> 4;
                const int cg = idx & 15;
                int gr = t0 + r;
                gr = gr < (T_IN - 1) ? gr : (T_IN - 1);   // clamp (last tile only; discarded)
                st[i] = *(const float4*)(x + ((size_t)bb * T_IN + gr) * CIN + cg * 4);
            }
        }
#pragma unroll
        for (int i = 0; i < CPT; ++i) {
            const int idx = i * 256 + tid;
            if (idx < CHUNKS) {
                const int r  = idx >> 4;
                const int cg = idx & 15;
                u16x4 p;
                p[0] = f2bf(st[i].x); p[1] = f2bf(st[i].y);
                p[2] = f2bf(st[i].z); p[3] = f2bf(st[i].w);
                *(u16x4*)&ldsX[0][r * LDS_STRIDE + cg * 4] = p;
            }
        }
    }
    __syncthreads();

    for (int it = 0; it < TILE_ITERS; ++it) {
        const int g   = blockIdx.x * TILE_ITERS + it;   // global tile id, 0..4095
        const int bb  = g >> 7;                         // batch
        const int t0  = (g & 127) << 7;                 // first output row of tile
        const int cur = it & 1;
        const bool more = (it + 1 < TILE_ITERS);

        // ---- Issue global loads for the NEXT tile (latency hides under MFMA) ----
        if (more) {
            const int gn  = g + 1;                      // <= 4095, always valid
            const int bbn = gn >> 7;
            const int t0n = (gn & 127) << 7;
#pragma unroll
            for (int i = 0; i < CPT; ++i) {
                const int idx = i * 256 + tid;
                if (idx < CHUNKS) {
                    const int r  = idx >> 4;
                    const int cg = idx & 15;
                    int gr = t0n + r;
                    gr = gr < (T_IN - 1) ? gr : (T_IN - 1);
                    st[i] = *(const float4*)(x + ((size_t)bbn * T_IN + gr) * CIN + cg * 4);
                }
            }
        }

        // ---- MFMA main loop on buffer `cur` ----
        f32x16 acc0 = {0,0,0,0,0,0,0,0,0,0,0,0,0,0,0,0};
        f32x16 acc1 = {0,0,0,0,0,0,0,0,0,0,0,0,0,0,0,0};
        // A-fragment: m = lane&31 (time row), k_inner = half*8+j (channel within 16-block)
        const unsigned short* lx = ldsX[cur];
        const int abase = (rbase + l31) * LDS_STRIDE + half * 8;
#pragma unroll
        for (int k = 0; k < KT; ++k) {
#pragma unroll
            for (int s = 0; s < 4; ++s) {
                const int off = abase + k * LDS_STRIDE + s * 16;
                bf16x8 a0 = *(const bf16x8*)&lx[off];
                bf16x8 a1 = *(const bf16x8*)&lx[off + 32 * LDS_STRIDE];
                acc0 = __builtin_amdgcn_mfma_f32_32x32x16_bf16(a0, Bf[k][s], acc0, 0, 0, 0);
                acc1 = __builtin_amdgcn_mfma_f32_32x32x16_bf16(a1, Bf[k][s], acc1, 0, 0, 0);
            }
        }

        // ---- Convert + write NEXT tile into the other buffer ----
        if (more) {
#pragma unroll
            for (int i = 0; i < CPT; ++i) {
                const int idx = i * 256 + tid;
                if (idx < CHUNKS) {
                    const int r  = idx >> 4;
                    const int cg = idx & 15;
                    u16x4 p;
                    p[0] = f2bf(st[i].x); p[1] = f2bf(st[i].y);
                    p[2] = f2bf(st[i].z); p[3] = f2bf(st[i].w);
                    *(u16x4*)&ldsX[cur ^ 1][r * LDS_STRIDE + cg * 4] = p;
                }
            }
            __syncthreads();   // orders: MFMA reads of buf[cur] before next write of buf[cur];
                               //         writes of buf[cur^1] before next MFMA reads it
        }

        // ---- Epilogue AFTER barrier: stores drain under next iteration's work ----
        // C/D layout col=lane&31, row=(reg&3)+8*(reg>>2)+4*(lane>>5)
#pragma unroll
        for (int m = 0; m < 2; ++m) {
            const f32x16 A = m ? acc1 : acc0;
#pragma unroll
            for (int r = 0; r < 16; ++r) {
                const int tl = rbase + m * 32 + (r & 3) + 8 * (r >> 2) + 4 * half;
                const int tg = t0 + tl;
                if (tg < T_OUT)
                    out[((size_t)bb * T_OUT + tg) * NF + fcol] = A[r] + bias;
            }
        }
    }
}

extern "C" void kernel_launch(void* const* d_in, const int* in_sizes, int n_in,
                              void* d_out, int out_size, void* d_ws, size_t ws_size,
                              hipStream_t stream) {
    const float* x = (const float*)d_in[0];
    const float* w = (const float*)d_in[1];
    const float* b = (const float*)d_in[2];
    float* out = (float*)d_out;
    conv1d_mfma_kernel<<<NBLOCKS, 256, 0, stream>>>(x, w, b, out);
}

// Round 2
// 291.079 us; speedup vs baseline: 1.0440x; 1.0440x over previous
//
#include <hip/hip_runtime.h>
#include <hip/hip_bf16.h>

// Problem constants
#define T_IN   16384
#define T_OUT  16376
#define CIN    64
#define NF     64
#define KT     9
#define NB     32
#define TILE   128                 // output rows per tile
#define ROWS   (TILE + KT - 1)     // 136 staged input rows
#define LDS_STRIDE 72              // shorts per row: 64 + 8 pad (144 B, breaks 128B stride)
#define TILES_PER_BATCH 128        // ceil(16376/128); last tile has 120 valid rows
#define NTILES (NB * TILES_PER_BATCH)   // 4096
#define NBLOCKS 512
#define TILE_ITERS (NTILES / NBLOCKS)   // 8
#define CHUNKS (ROWS * 16)         // 2176 float4 chunks per tile
#define DMA_INSTR (ROWS / 4)       // 34 wave-instructions, 4 fp32 rows (1024B) each

typedef __bf16 bf16x8 __attribute__((ext_vector_type(8)));
typedef unsigned short u16x8 __attribute__((ext_vector_type(8)));
typedef unsigned short u16x4 __attribute__((ext_vector_type(4)));
typedef float f32x16 __attribute__((ext_vector_type(16)));

// fp32 -> bf16 round-to-nearest-even (bit twiddle; avoids relying on __bf16 conversions)
__device__ __forceinline__ unsigned short f2bf(float f) {
    unsigned u = __builtin_bit_cast(unsigned, f);
    u += 0x7FFFu + ((u >> 16) & 1u);
    return (unsigned short)(u >> 16);
}

// Async global->LDS DMA, 16B per lane. LDS dest is wave-uniform base + lane*16.
__device__ __forceinline__ void async_load16(const float* g, float* l) {
    __builtin_amdgcn_global_load_lds(
        (const __attribute__((address_space(1))) void*)g,
        (__attribute__((address_space(3))) void*)l, 16, 0, 0);
}

__global__ __launch_bounds__(256, 2) void conv1d_mfma_kernel(
    const float* __restrict__ x,   // [32][16384][64]
    const float* __restrict__ w,   // [64][9][64]
    const float* __restrict__ b,   // [64]
    float* __restrict__ out)       // [32][16376][64]
{
    // fp32 staging buffer (linear, DMA target) + bf16 compute buffer (padded)
    __shared__ __attribute__((aligned(16))) float          f32X[ROWS * CIN];         // 34816 B
    __shared__ __attribute__((aligned(16))) unsigned short ldsX[ROWS * LDS_STRIDE];  // 19584 B

    const int tid  = threadIdx.x;
    const int lane = tid & 63;
    const int wv   = tid >> 6;        // 4 waves
    const int half = lane >> 5;       // 0/1: k-half of MFMA operand
    const int l31  = lane & 31;
    const int fh   = wv & 1;          // filter half (0: f 0..31, 1: f 32..63)
    const int rh   = wv >> 1;         // row half (0: rows 0..63, 1: rows 64..127)
    const int fbase = fh * 32;
    const int rbase = rh * 64;
    const int fcol  = fbase + l31;    // this lane's output filter column

    // DMA lane decomposition: instr j covers rows 4j..4j+3; lane = row(2b) x chunk(4b)
    const int dma_r = lane >> 4;           // row within 4-row group
    const int dma_c = (lane & 15) << 2;    // float offset within row (16B chunk)

    // ---- Load all weight B-fragments into registers (once per block) ----
    // B[k_inner][n] layout for mfma_f32_32x32x16_bf16: n = lane&31, k_inner = (lane>>5)*8 + j
    // Global w element: w[f][tap][c], c = s*16 + half*8 + j
    bf16x8 Bf[KT][4];
#pragma unroll
    for (int k = 0; k < KT; ++k) {
#pragma unroll
        for (int s = 0; s < 4; ++s) {
            const float* wp = w + (size_t)fcol * (KT * CIN) + k * CIN + s * 16 + half * 8;
            const float4 w0 = *(const float4*)(wp);
            const float4 w1 = *(const float4*)(wp + 4);
            u16x8 t;
            t[0] = f2bf(w0.x); t[1] = f2bf(w0.y); t[2] = f2bf(w0.z); t[3] = f2bf(w0.w);
            t[4] = f2bf(w1.x); t[5] = f2bf(w1.y); t[6] = f2bf(w1.z); t[7] = f2bf(w1.w);
            Bf[k][s] = __builtin_bit_cast(bf16x8, t);
        }
    }
    const float bias = b[fcol];

    // ---- Stage tile g's fp32 rows into f32X via async DMA (no regs, no VALU) ----
    auto stage = [&](int g) {
        const int bb = g >> 7;
        const int t0 = (g & 127) << 7;
        for (int j = wv; j < DMA_INSTR; j += 4) {
            int gr = t0 + j * 4 + dma_r;
            gr = gr < (T_IN - 1) ? gr : (T_IN - 1);   // clamp (last tile only; discarded)
            const float* gp = x + ((size_t)bb * T_IN + gr) * CIN + dma_c;
            async_load16(gp, &f32X[j * 256]);
        }
    };

    // ---- LDS fp32 -> LDS bf16 convert pass (contiguous b128 reads, conflict-free) ----
    auto convert = [&]() {
        for (int i = tid; i < CHUNKS; i += 256) {
            const float4 v = *(const float4*)&f32X[i * 4];
            const int r  = i >> 4;
            const int cg = i & 15;
            u16x4 p;
            p[0] = f2bf(v.x); p[1] = f2bf(v.y); p[2] = f2bf(v.z); p[3] = f2bf(v.w);
            *(u16x4*)&ldsX[r * LDS_STRIDE + cg * 4] = p;
        }
    };

    // ---- Prologue: stage + convert tile 0 ----
    stage(blockIdx.x * TILE_ITERS);
    __syncthreads();                 // vmcnt(0) drain = DMA arrival
    convert();
    __syncthreads();

    for (int it = 0; it < TILE_ITERS; ++it) {
        const int g   = blockIdx.x * TILE_ITERS + it;   // global tile id, 0..4095
        const int bb  = g >> 7;                         // batch
        const int t0  = (g & 127) << 7;                 // first output row of tile
        const bool more = (it + 1 < TILE_ITERS);

        // Issue async DMA for the NEXT tile; it flies under the MFMA phase.
        // f32X currently holds tile g's fp32 data, already converted -> dead.
        if (more) stage(g + 1);

        // ---- MFMA main loop on ldsX (tile g) ----
        f32x16 acc0 = {0,0,0,0,0,0,0,0,0,0,0,0,0,0,0,0};
        f32x16 acc1 = {0,0,0,0,0,0,0,0,0,0,0,0,0,0,0,0};
        // A-fragment: m = lane&31 (time row), k_inner = half*8+j (channel within 16-block)
        const int abase = (rbase + l31) * LDS_STRIDE + half * 8;
#pragma unroll
        for (int k = 0; k < KT; ++k) {
#pragma unroll
            for (int s = 0; s < 4; ++s) {
                const int off = abase + k * LDS_STRIDE + s * 16;
                bf16x8 a0 = *(const bf16x8*)&ldsX[off];
                bf16x8 a1 = *(const bf16x8*)&ldsX[off + 32 * LDS_STRIDE];
                acc0 = __builtin_amdgcn_mfma_f32_32x32x16_bf16(a0, Bf[k][s], acc0, 0, 0, 0);
                acc1 = __builtin_amdgcn_mfma_f32_32x32x16_bf16(a1, Bf[k][s], acc1, 0, 0, 0);
            }
        }

        __syncthreads();   // own vmcnt(0) drained by compiler: next tile's DMA has landed;
                           // also all ldsX reads of tile g are done
        if (more) convert();            // f32X(tile g+1) -> ldsX
        __syncthreads();   // ldsX ready; f32X free for next stage()

        // ---- Epilogue AFTER barriers: stores drain under next iteration's work ----
        // C/D layout col=lane&31, row=(reg&3)+8*(reg>>2)+4*(lane>>5)
#pragma unroll
        for (int m = 0; m < 2; ++m) {
            const f32x16 A = m ? acc1 : acc0;
#pragma unroll
            for (int r = 0; r < 16; ++r) {
                const int tl = rbase + m * 32 + (r & 3) + 8 * (r >> 2) + 4 * half;
                const int tg = t0 + tl;
                if (tg < T_OUT)
                    out[((size_t)bb * T_OUT + tg) * NF + fcol] = A[r] + bias;
            }
        }
    }
}

extern "C" void kernel_launch(void* const* d_in, const int* in_sizes, int n_in,
                              void* d_out, int out_size, void* d_ws, size_t ws_size,
                              hipStream_t stream) {
    const float* x = (const float*)d_in[0];
    const float* w = (const float*)d_in[1];
    const float* b = (const float*)d_in[2];
    float* out = (float*)d_out;
    conv1d_mfma_kernel<<<NBLOCKS, 256, 0, stream>>>(x, w, b, out);
}